// Round 9
// baseline (95.186 us; speedup 1.0000x reference)
//
#include <hip/hip_runtime.h>
#include <hip/hip_bf16.h>

#define NN 100000
#define NE 1000000
#define D 64
#define NG 125             // nodes per group; 800 groups
#define NGR 800
#define NB 128             // bin blocks
#define EPB 7813           // ceil(NE/NB)
#define RCAP 40            // per-(group,block) region capacity (mean 9.8, P(ovf)~1e-13)

typedef unsigned int  u32;
typedef unsigned short u16;
typedef __attribute__((ext_vector_type(8))) short bf16x8;
typedef __attribute__((ext_vector_type(4))) float f32x4;

static __device__ __forceinline__ short bfs(float f) {
    union { __hip_bfloat16 h; short s; } u;
    u.h = __float2bfloat16(f);
    return u.s;
}

// ---------------- pass 1: bin edges into 800 node-groups ----------------
// packed edge: src | (dst_local << 17)  (src < 2^17, dst_local < 125)
// regions bins[(g*NB + blk)*RCAP] are block-private -> no shared dirty lines.
__global__ __launch_bounds__(256) void bin_kernel(const int* __restrict__ src,
                                                  const int* __restrict__ dst,
                                                  u32* __restrict__ bins,
                                                  int* __restrict__ cnt800) {
    __shared__ int lcur[NGR];
    const int t = threadIdx.x, blk = blockIdx.x;
    for (int i = t; i < NGR; i += 256) lcur[i] = 0;
    __syncthreads();
    const int e0 = blk * EPB;
    int e1 = e0 + EPB; if (e1 > NE) e1 = NE;
    for (int e = e0 + t; e < e1; e += 256) {
        int d = dst[e], s = src[e];
        int g  = d / NG;                        // const-div -> magic mul
        int nl = d - g * NG;
        int pos = atomicAdd(&lcur[g], 1);       // LDS atomic
        if (pos < RCAP)
            bins[((size_t)g * NB + blk) * RCAP + pos] = (u32)s | ((u32)nl << 17);
    }
    __syncthreads();
    for (int i = t; i < NGR; i += 256) cnt800[blk * NGR + i] = lcur[i];  // coalesced
}

// ---------------- pass 2: build slot table in LDS, write cnt+esrc coalesced ----------------
// one block per 125-node group; flat slot-scan (independent predicated loads).
__global__ __launch_bounds__(256) void build_kernel(const u32* __restrict__ bins,
                                                    const int* __restrict__ cnt800,
                                                    int* __restrict__ cnt,
                                                    int* __restrict__ esrc) {
    __shared__ int lcnt[NG];
    __shared__ int lslots[NG * 32];
    __shared__ int ccnt[NB];
    const int g = blockIdx.x;
    const int t = threadIdx.x;
    if (t < NG) lcnt[t] = 0;
    if (t < NB) {
        int c = cnt800[t * NGR + g];             // strided, line-shared across groups (L2)
        ccnt[t] = c < RCAP ? c : RCAP;           // clamp: never scan unwritten slots
    }
    __syncthreads();
    const u32* p = &bins[(size_t)g * NB * RCAP];
    for (int i = t; i < NB * RCAP; i += 256) {   // 20 iters, loads independent
        int cell = i / RCAP;                     // const-div
        int si   = i - cell * RCAP;
        if (si < ccnt[cell]) {
            u32 v = p[i];
            int nl = (int)(v >> 17);
            int pos = atomicAdd(&lcnt[nl], 1);   // LDS atomic
            if (pos < 32) lslots[nl * 32 + pos] = (int)(v & 0x1FFFFu);
        }
    }
    __syncthreads();
    const int nb = g * NG;
    if (t < NG) cnt[nb + t] = lcnt[t];
    for (int i = t; i < NG * 32; i += 256)       // coalesced full-line store
        esrc[nb * 32 + i] = lslots[i];
}

// ---------------- MFMA GEMM: xs = dinv * (x @ W^T) in bf16 ----------------
__global__ __launch_bounds__(256) void gemm_kernel(const float* __restrict__ x,
                                                   const float* __restrict__ W,
                                                   const int* __restrict__ cnt,
                                                   u16* __restrict__ xs_out) {
    const int t = threadIdx.x;
    if (blockIdx.x == 0 && t < 8)
        *reinterpret_cast<uint4*>(&xs_out[(size_t)NN * D + t * 8]) = make_uint4(0u, 0u, 0u, 0u);

    const int wv  = t >> 6;
    const int l   = t & 63;
    const int job = blockIdx.x * 4 + wv;
    if (job >= NN / 16) return;
    const int r0  = job * 16;
    const int lr  = l & 15;
    const int lg  = l >> 4;

    bf16x8 bfr[4][2];
#pragma unroll
    for (int ct = 0; ct < 4; ++ct) {
#pragma unroll
        for (int h = 0; h < 2; ++h) {
            const float* wp = &W[(ct * 16 + lr) * 64 + h * 32 + lg * 8];
            float4 w0 = *reinterpret_cast<const float4*>(wp);
            float4 w1 = *reinterpret_cast<const float4*>(wp + 4);
            bf16x8 v;
            v[0] = bfs(w0.x); v[1] = bfs(w0.y); v[2] = bfs(w0.z); v[3] = bfs(w0.w);
            v[4] = bfs(w1.x); v[5] = bfs(w1.y); v[6] = bfs(w1.z); v[7] = bfs(w1.w);
            bfr[ct][h] = v;
        }
    }
    bf16x8 afr[2];
#pragma unroll
    for (int h = 0; h < 2; ++h) {
        const float* xp = &x[(size_t)(r0 + lr) * D + h * 32 + lg * 8];
        float4 x0 = *reinterpret_cast<const float4*>(xp);
        float4 x1 = *reinterpret_cast<const float4*>(xp + 4);
        bf16x8 v;
        v[0] = bfs(x0.x); v[1] = bfs(x0.y); v[2] = bfs(x0.z); v[3] = bfs(x0.w);
        v[4] = bfs(x1.x); v[5] = bfs(x1.y); v[6] = bfs(x1.z); v[7] = bfs(x1.w);
        afr[h] = v;
    }

    f32x4 acc[4];
#pragma unroll
    for (int ct = 0; ct < 4; ++ct) acc[ct] = (f32x4){0.f, 0.f, 0.f, 0.f};
#pragma unroll
    for (int ct = 0; ct < 4; ++ct) {
        acc[ct] = __builtin_amdgcn_mfma_f32_16x16x32_bf16(afr[0], bfr[ct][0], acc[ct], 0, 0, 0);
        acc[ct] = __builtin_amdgcn_mfma_f32_16x16x32_bf16(afr[1], bfr[ct][1], acc[ct], 0, 0, 0);
    }

    float dd[4];
#pragma unroll
    for (int j = 0; j < 4; ++j)
        dd[j] = rsqrtf((float)cnt[r0 + lg * 4 + j] + 2.0f);
#pragma unroll
    for (int ct = 0; ct < 4; ++ct)
#pragma unroll
        for (int j = 0; j < 4; ++j)
            xs_out[(size_t)(r0 + lg * 4 + j) * D + ct * 16 + lr] = (u16)bfs(dd[j] * acc[ct][j]);
}

// ---------------- fused gather + self-loop + bias + relu ----------------
// one wave per node; 8 lanes per edge (uint4 = 8 channels) -> 8 edges/iter.
__global__ __launch_bounds__(256) void gather_kernel(const int* __restrict__ cnt,
                                                     const int* __restrict__ esrc,
                                                     const u32* __restrict__ xs,
                                                     const float* __restrict__ b,
                                                     float* __restrict__ out) {
    const int lane = threadIdx.x & 63;
    const int node = (blockIdx.x * 256 + threadIdx.x) >> 6;
    if (node >= NN) return;
    const int mraw = cnt[node];
    const int m    = mraw < 32 ? mraw : 32;
    const int g    = lane >> 3;        // edge sub-slot 0..7
    const int c8   = lane & 7;         // channel octet

    int s = esrc[node * 32 + (lane & 31)];   // slots >= m are garbage, masked below

    float a0 = 0, a1 = 0, a2 = 0, a3 = 0, a4 = 0, a5 = 0, a6 = 0, a7 = 0;
    const int iters = (m + 7) >> 3;

#define BODY(kk) {                                                              \
        int idx = (kk) * 8 + g;                                                 \
        int sj = __shfl(s, idx);                                                \
        sj = (idx < m) ? sj : NN;                                               \
        uint4 u = *reinterpret_cast<const uint4*>(&xs[sj * 32 + c8 * 4]);       \
        a0 += __uint_as_float(u.x << 16); a1 += __uint_as_float(u.x & 0xffff0000u); \
        a2 += __uint_as_float(u.y << 16); a3 += __uint_as_float(u.y & 0xffff0000u); \
        a4 += __uint_as_float(u.z << 16); a5 += __uint_as_float(u.z & 0xffff0000u); \
        a6 += __uint_as_float(u.w << 16); a7 += __uint_as_float(u.w & 0xffff0000u); }

    BODY(0)                                      // m <= 8: one batch (33% of nodes)
    if (m > 8) BODY(1)
    for (int k = 2; k < iters; ++k) { BODY(k) }  // rare tail (m <= 32)
#undef BODY

#define RED(a) { a += __shfl(a, lane ^ 8); a += __shfl(a, lane ^ 16); a += __shfl(a, lane ^ 32); }
    RED(a0) RED(a1) RED(a2) RED(a3) RED(a4) RED(a5) RED(a6) RED(a7)
#undef RED

    if (g == 0) {
        float dd = rsqrtf((float)mraw + 2.0f);
        uint4 su = *reinterpret_cast<const uint4*>(&xs[node * 32 + c8 * 4]);
        float4 bb0 = *reinterpret_cast<const float4*>(&b[c8 * 8]);
        float4 bb1 = *reinterpret_cast<const float4*>(&b[c8 * 8 + 4]);
        float s0 = __uint_as_float(su.x << 16), s1 = __uint_as_float(su.x & 0xffff0000u);
        float s2 = __uint_as_float(su.y << 16), s3 = __uint_as_float(su.y & 0xffff0000u);
        float s4 = __uint_as_float(su.z << 16), s5 = __uint_as_float(su.z & 0xffff0000u);
        float s6 = __uint_as_float(su.w << 16), s7 = __uint_as_float(su.w & 0xffff0000u);
        float td = 2.0f * dd;
        float4 o0, o1;
        o0.x = fmaxf(fmaf(dd, a0, fmaf(td, s0, bb0.x)), 0.f);
        o0.y = fmaxf(fmaf(dd, a1, fmaf(td, s1, bb0.y)), 0.f);
        o0.z = fmaxf(fmaf(dd, a2, fmaf(td, s2, bb0.z)), 0.f);
        o0.w = fmaxf(fmaf(dd, a3, fmaf(td, s3, bb0.w)), 0.f);
        o1.x = fmaxf(fmaf(dd, a4, fmaf(td, s4, bb1.x)), 0.f);
        o1.y = fmaxf(fmaf(dd, a5, fmaf(td, s5, bb1.y)), 0.f);
        o1.z = fmaxf(fmaf(dd, a6, fmaf(td, s6, bb1.z)), 0.f);
        o1.w = fmaxf(fmaf(dd, a7, fmaf(td, s7, bb1.w)), 0.f);
        *reinterpret_cast<float4*>(&out[node * D + c8 * 8])     = o0;
        *reinterpret_cast<float4*>(&out[node * D + c8 * 8 + 4]) = o1;
    }
}

extern "C" void kernel_launch(void* const* d_in, const int* in_sizes, int n_in,
                              void* d_out, int out_size, void* d_ws, size_t ws_size,
                              hipStream_t stream) {
    const float* x  = (const float*)d_in[0];
    const int*   ei = (const int*)d_in[1];      // (2, NE) row-major int32
    const float* W  = (const float*)d_in[2];
    const float* b  = (const float*)d_in[3];
    const int* src = ei;
    const int* dst = ei + NE;
    float* out = (float*)d_out;

    // workspace (u32 units), total 30.0 MB.
    // bins and xsb UNION the base region: bins dies at build_kernel, xsb is
    // written afterwards by gemm_kernel (stream-ordered); every byte gather
    // reads (incl. zero row NN) is rewritten each replay -> no stale state.
    u32* base   = (u32*)d_ws;
    u32* bins   = base;                          // 800*128*40 = 4,096,000 u32
    u16* xsb    = (u16*)d_ws;                    // (NN+1)*64 bf16 = 1,600,016 u32 (aliases bins)
    int* cnt800 = (int*)(base + 4096000);        // 128*800 = 102,400
    int* cnt    = (int*)(base + 4198400);        // 100,000
    int* esrc   = (int*)(base + 4298400);        // NN*32 = 3,200,000 (byte off %128 == 0)

    bin_kernel   <<<NB, 256, 0, stream>>>(src, dst, bins, cnt800);
    build_kernel <<<NGR, 256, 0, stream>>>(bins, cnt800, cnt, esrc);
    gemm_kernel  <<<(NN + 63) / 64, 256, 0, stream>>>(x, W, cnt, xsb);
    gather_kernel<<<(NN * 64 + 255) / 256, 256, 0, stream>>>(cnt, esrc, (const u32*)xsb, b, out);
}

// Round 11
// 89.573 us; speedup vs baseline: 1.0627x; 1.0627x over previous
//
#include <hip/hip_runtime.h>
#include <hip/hip_bf16.h>

#define NN 100000
#define NE 1000000
#define D 64
#define BIN_T 4096
#define NB1 245            // ceil(NE / BIN_T)
#define BCAP 768           // per-(block,xcd-bucket) capacity; mean 512
#define CAP2 96            // per-(block,group) cell capacity; mean 39
#define NR 12500           // nodes per XCD bucket
#define NG 125             // nodes per group (100 groups per XCD, 800 total)

typedef unsigned int  u32;
typedef unsigned short u16;
typedef __attribute__((ext_vector_type(8))) short bf16x8;
typedef __attribute__((ext_vector_type(4))) float f32x4;

static __device__ __forceinline__ short bfs(float f) {
    union { __hip_bfloat16 h; short s; } u;
    u.h = __float2bfloat16(f);
    return u.s;
}

// ---------------- pass 1: bin edges into 8 XCD buckets ----------------
// packed edge: src | (dst_local << 17)  (src < 2^17, dst_local < 2^14)
__global__ __launch_bounds__(256) void bin8_kernel(const int* __restrict__ src,
                                                   const int* __restrict__ dst,
                                                   u32* __restrict__ bins8,
                                                   int* __restrict__ bcnt8) {
    __shared__ int lcur[8];
    const int t = threadIdx.x;
    const int blk = blockIdx.x;
    if (t < 8) lcur[t] = 0;
    __syncthreads();
    const int base = blk * BIN_T;
#pragma unroll
    for (int i = 0; i < 16; ++i) {
        int e = base + i * 256 + t;
        if (e < NE) {
            int d = dst[e];
            int s = src[e];
            int bk = d / NR;
            int pos = atomicAdd(&lcur[bk], 1);
            if (pos < BCAP)
                bins8[(blk * 8 + bk) * BCAP + pos] = (u32)s | ((u32)(d - bk * NR) << 17);
        }
    }
    __syncthreads();
    if (t < 8) bcnt8[blk * 8 + t] = lcur[t];
}

// ---------------- pass 2: sub-bin each XCD bucket into 100 groups ----------------
__global__ __launch_bounds__(256) void bin100_kernel(const u32* __restrict__ bins8,
                                                     const int* __restrict__ bcnt8,
                                                     u32* __restrict__ bins100,
                                                     int* __restrict__ cnt100) {
    __shared__ int lcur[100];
    const int bi = blockIdx.x;          // 0..255
    const int r = bi & 7, j = bi >> 3;  // xcd, slice
    const int t = threadIdx.x;
    const int wid = t >> 6, lane = t & 63;
    if (t < 100) lcur[t] = 0;
    __syncthreads();
    const int f0 = (NB1 * j) >> 5, f1 = (NB1 * (j + 1)) >> 5;
    for (int f = f0 + wid; f < f1; f += 4) {
        int n = bcnt8[f * 8 + r];
        if (n > BCAP) n = BCAP;
        const u32* p = &bins8[(f * 8 + r) * BCAP];
        for (int i = lane; i < n; i += 64) {
            u32 v = p[i];
            int q = (int)(v >> 17) / NG;              // group 0..99
            int pos = atomicAdd(&lcur[q], 1);         // LDS atomic
            if (pos < CAP2) bins100[(bi * 100 + q) * CAP2 + pos] = v;
        }
    }
    __syncthreads();
    if (t < 100) cnt100[bi * 100 + t] = lcur[t];
}

// ---------------- pass 3: build slot table in LDS, write cnt+esrc coalesced ----------------
__global__ __launch_bounds__(256) void build_kernel(const u32* __restrict__ bins100,
                                                    const int* __restrict__ cnt100,
                                                    int* __restrict__ cnt,
                                                    int* __restrict__ esrc) {
    __shared__ int lcnt[NG];
    __shared__ int lslots[NG * 32];
    __shared__ int ccnt[32];
    const int g = blockIdx.x;           // 0..799
    const int r = g & 7, q = g >> 3;    // xcd, group
    const int t = threadIdx.x;
    if (t < NG) lcnt[t] = 0;
    if (t < 32) {
        int n = cnt100[((t << 3) | r) * 100 + q];
        ccnt[t] = n < CAP2 ? n : CAP2;  // clamp: never scan unwritten slots
    }
    __syncthreads();
    for (int i = t; i < 32 * CAP2; i += 256) {   // flat slot-scan, loads independent
        int j = i / CAP2;                        // const-div
        int si = i - j * CAP2;
        if (si < ccnt[j]) {
            u32 v = bins100[(size_t)(((j << 3) | r) * 100 + q) * CAP2 + si];
            int nl = (int)(v >> 17) - q * NG;
            int pos = atomicAdd(&lcnt[nl], 1);   // LDS atomic
            if (pos < 32) lslots[nl * 32 + pos] = (int)(v & 0x1FFFFu);
        }
    }
    __syncthreads();
    const int nb = r * NR + q * NG;
    if (t < NG) cnt[nb + t] = lcnt[t];
    for (int i = t; i < NG * 32; i += 256)       // coalesced full-line store
        esrc[nb * 32 + i] = lslots[i];
}

// ---------------- MFMA GEMM: xs = dinv * (x @ W^T) in bf16 ----------------
__global__ __launch_bounds__(256) void gemm_kernel(const float* __restrict__ x,
                                                   const float* __restrict__ W,
                                                   const int* __restrict__ cnt,
                                                   u16* __restrict__ xs_out) {
    const int t = threadIdx.x;
    if (blockIdx.x == 0 && t < 8)       // zero row NN (gather's mask target)
        *reinterpret_cast<uint4*>(&xs_out[(size_t)NN * D + t * 8]) = make_uint4(0u, 0u, 0u, 0u);

    const int wv  = t >> 6;
    const int l   = t & 63;
    const int job = blockIdx.x * 4 + wv;
    if (job >= NN / 16) return;
    const int r0  = job * 16;
    const int lr  = l & 15;
    const int lg  = l >> 4;

    bf16x8 bfr[4][2];
#pragma unroll
    for (int ct = 0; ct < 4; ++ct) {
#pragma unroll
        for (int h = 0; h < 2; ++h) {
            const float* wp = &W[(ct * 16 + lr) * 64 + h * 32 + lg * 8];
            float4 w0 = *reinterpret_cast<const float4*>(wp);
            float4 w1 = *reinterpret_cast<const float4*>(wp + 4);
            bf16x8 v;
            v[0] = bfs(w0.x); v[1] = bfs(w0.y); v[2] = bfs(w0.z); v[3] = bfs(w0.w);
            v[4] = bfs(w1.x); v[5] = bfs(w1.y); v[6] = bfs(w1.z); v[7] = bfs(w1.w);
            bfr[ct][h] = v;
        }
    }
    bf16x8 afr[2];
#pragma unroll
    for (int h = 0; h < 2; ++h) {
        const float* xp = &x[(size_t)(r0 + lr) * D + h * 32 + lg * 8];
        float4 x0 = *reinterpret_cast<const float4*>(xp);
        float4 x1 = *reinterpret_cast<const float4*>(xp + 4);
        bf16x8 v;
        v[0] = bfs(x0.x); v[1] = bfs(x0.y); v[2] = bfs(x0.z); v[3] = bfs(x0.w);
        v[4] = bfs(x1.x); v[5] = bfs(x1.y); v[6] = bfs(x1.z); v[7] = bfs(x1.w);
        afr[h] = v;
    }

    f32x4 acc[4];
#pragma unroll
    for (int ct = 0; ct < 4; ++ct) acc[ct] = (f32x4){0.f, 0.f, 0.f, 0.f};
#pragma unroll
    for (int ct = 0; ct < 4; ++ct) {
        acc[ct] = __builtin_amdgcn_mfma_f32_16x16x32_bf16(afr[0], bfr[ct][0], acc[ct], 0, 0, 0);
        acc[ct] = __builtin_amdgcn_mfma_f32_16x16x32_bf16(afr[1], bfr[ct][1], acc[ct], 0, 0, 0);
    }

    float dd[4];
#pragma unroll
    for (int j = 0; j < 4; ++j)
        dd[j] = rsqrtf((float)cnt[r0 + lg * 4 + j] + 2.0f);
#pragma unroll
    for (int ct = 0; ct < 4; ++ct)
#pragma unroll
        for (int j = 0; j < 4; ++j)
            xs_out[(size_t)(r0 + lg * 4 + j) * D + ct * 16 + lr] = (u16)bfs(dd[j] * acc[ct][j]);
}

// ---------------- fused gather + self-loop + bias + relu ----------------
// TWO nodes per wave, interleaved -> 4 independent gather chains in flight.
// 8 lanes per edge (uint4 = 8 channels); masked slots -> zero row NN.
__global__ __launch_bounds__(256) void gather_kernel(const int* __restrict__ cnt,
                                                     const int* __restrict__ esrc,
                                                     const u32* __restrict__ xs,
                                                     const float* __restrict__ b,
                                                     float* __restrict__ out) {
    const int lane = threadIdx.x & 63;
    const int wp   = (blockIdx.x * 256 + threadIdx.x) >> 6;   // wave-pair id
    const int n0 = wp * 2, n1 = n0 + 1;
    if (n0 >= NN) return;
    const int m0r = cnt[n0], m1r = cnt[n1];
    const int m0 = m0r < 32 ? m0r : 32;
    const int m1 = m1r < 32 ? m1r : 32;
    const int g  = lane >> 3;          // edge sub-slot 0..7
    const int c8 = lane & 7;           // channel octet

    int s0 = esrc[n0 * 32 + (lane & 31)];
    int s1 = esrc[n1 * 32 + (lane & 31)];

    float a0 = 0, a1 = 0, a2 = 0, a3 = 0, a4 = 0, a5 = 0, a6 = 0, a7 = 0;
    float b0 = 0, b1 = 0, b2 = 0, b3 = 0, b4 = 0, b5 = 0, b6 = 0, b7 = 0;

#define BODY(S, M, P0,P1,P2,P3,P4,P5,P6,P7, KK) {                               \
        int idx = (KK) * 8 + g;                                                 \
        int sj = __shfl(S, idx);                                                \
        sj = (idx < (M)) ? sj : NN;                                             \
        uint4 u = *reinterpret_cast<const uint4*>(&xs[sj * 32 + c8 * 4]);       \
        P0 += __uint_as_float(u.x << 16); P1 += __uint_as_float(u.x & 0xffff0000u); \
        P2 += __uint_as_float(u.y << 16); P3 += __uint_as_float(u.y & 0xffff0000u); \
        P4 += __uint_as_float(u.z << 16); P5 += __uint_as_float(u.z & 0xffff0000u); \
        P6 += __uint_as_float(u.w << 16); P7 += __uint_as_float(u.w & 0xffff0000u); }

    // batch 0 for both nodes unconditionally (2 loads in flight) ...
    BODY(s0, m0, a0,a1,a2,a3,a4,a5,a6,a7, 0)
    BODY(s1, m1, b0,b1,b2,b3,b4,b5,b6,b7, 0)
    // ... batch 1 conditionally (wave-uniform branches), still overlapped
    if (m0 > 8)  BODY(s0, m0, a0,a1,a2,a3,a4,a5,a6,a7, 1)
    if (m1 > 8)  BODY(s1, m1, b0,b1,b2,b3,b4,b5,b6,b7, 1)
    if (m0 > 16) BODY(s0, m0, a0,a1,a2,a3,a4,a5,a6,a7, 2)
    if (m1 > 16) BODY(s1, m1, b0,b1,b2,b3,b4,b5,b6,b7, 2)
    if (m0 > 24) BODY(s0, m0, a0,a1,a2,a3,a4,a5,a6,a7, 3)
    if (m1 > 24) BODY(s1, m1, b0,b1,b2,b3,b4,b5,b6,b7, 3)
#undef BODY

#define RED(a) { a += __shfl(a, lane ^ 8); a += __shfl(a, lane ^ 16); a += __shfl(a, lane ^ 32); }
    RED(a0) RED(a1) RED(a2) RED(a3) RED(a4) RED(a5) RED(a6) RED(a7)
    RED(b0) RED(b1) RED(b2) RED(b3) RED(b4) RED(b5) RED(b6) RED(b7)
#undef RED

    if (g < 2) {                       // g==0 -> node0, g==1 -> node1
        const int  node = g ? n1 : n0;
        const int  mr   = g ? m1r : m0r;
        float v0 = g ? b0 : a0, v1 = g ? b1 : a1, v2 = g ? b2 : a2, v3 = g ? b3 : a3;
        float v4 = g ? b4 : a4, v5 = g ? b5 : a5, v6 = g ? b6 : a6, v7 = g ? b7 : a7;
        float dd = rsqrtf((float)mr + 2.0f);
        uint4 su = *reinterpret_cast<const uint4*>(&xs[node * 32 + c8 * 4]);
        float4 bb0 = *reinterpret_cast<const float4*>(&b[c8 * 8]);
        float4 bb1 = *reinterpret_cast<const float4*>(&b[c8 * 8 + 4]);
        float s0f = __uint_as_float(su.x << 16), s1f = __uint_as_float(su.x & 0xffff0000u);
        float s2f = __uint_as_float(su.y << 16), s3f = __uint_as_float(su.y & 0xffff0000u);
        float s4f = __uint_as_float(su.z << 16), s5f = __uint_as_float(su.z & 0xffff0000u);
        float s6f = __uint_as_float(su.w << 16), s7f = __uint_as_float(su.w & 0xffff0000u);
        float td = 2.0f * dd;
        float4 o0, o1;
        o0.x = fmaxf(fmaf(dd, v0, fmaf(td, s0f, bb0.x)), 0.f);
        o0.y = fmaxf(fmaf(dd, v1, fmaf(td, s1f, bb0.y)), 0.f);
        o0.z = fmaxf(fmaf(dd, v2, fmaf(td, s2f, bb0.z)), 0.f);
        o0.w = fmaxf(fmaf(dd, v3, fmaf(td, s3f, bb0.w)), 0.f);
        o1.x = fmaxf(fmaf(dd, v4, fmaf(td, s4f, bb1.x)), 0.f);
        o1.y = fmaxf(fmaf(dd, v5, fmaf(td, s5f, bb1.y)), 0.f);
        o1.z = fmaxf(fmaf(dd, v6, fmaf(td, s6f, bb1.z)), 0.f);
        o1.w = fmaxf(fmaf(dd, v7, fmaf(td, s7f, bb1.w)), 0.f);
        *reinterpret_cast<float4*>(&out[(size_t)node * D + c8 * 8])     = o0;
        *reinterpret_cast<float4*>(&out[(size_t)node * D + c8 * 8 + 4]) = o1;
    }
}

extern "C" void kernel_launch(void* const* d_in, const int* in_sizes, int n_in,
                              void* d_out, int out_size, void* d_ws, size_t ws_size,
                              hipStream_t stream) {
    const float* x  = (const float*)d_in[0];
    const int*   ei = (const int*)d_in[1];      // (2, NE) row-major int32
    const float* W  = (const float*)d_in[2];
    const float* b  = (const float*)d_in[3];
    const int* src = ei;
    const int* dst = ei + NE;
    float* out = (float*)d_out;

    // workspace (u32 units), total 29.5 MB (under the 30 MB proven envelope).
    // bins8 and xsb UNION region 0: bins8 (1,505,280) dies after bin100; xsb
    // (1,600,032) is written by gemm afterwards (stream-ordered). Every byte
    // read downstream is rewritten each replay -> replay-safe.
    u32* base    = (u32*)d_ws;
    u32* bins8   = base;                         // 1,505,280 u32
    u16* xsb     = (u16*)d_ws;                   // (NN+1)*64 bf16 = 1,600,032 u32
    u32* bins100 = base + 1600032;               // 2,457,600 u32
    int* cnt100  = (int*)(base + 4057632);       // 25,600
    int* cnt     = (int*)(base + 4083232);       // 100,000
    int* esrc    = (int*)(base + 4183232);       // NN*32 = 3,200,000 (byte off %128 == 0)
    int* bcnt8   = (int*)(base + 7383232);       // 1,960

    bin8_kernel  <<<NB1, 256, 0, stream>>>(src, dst, bins8, bcnt8);
    bin100_kernel<<<256, 256, 0, stream>>>(bins8, bcnt8, bins100, cnt100);
    build_kernel <<<800, 256, 0, stream>>>(bins100, cnt100, cnt, esrc);
    gemm_kernel  <<<(NN + 63) / 64, 256, 0, stream>>>(x, W, cnt, xsb);
    gather_kernel<<<(NN / 2 + 3) / 4, 256, 0, stream>>>(cnt, esrc, (const u32*)xsb, b, out);
}